// Round 4
// baseline (189.030 us; speedup 1.0000x reference)
//
#include <hip/hip_runtime.h>
#include <hip/hip_bf16.h>
#include <cstdint>
#include <cstddef>

typedef __bf16 bf16_t;
typedef __bf16 bf16x8 __attribute__((ext_vector_type(8)));
typedef __bf16 bf16x4 __attribute__((ext_vector_type(4)));
typedef float f32x4 __attribute__((ext_vector_type(4)));

#define DEVINL __device__ __forceinline__

DEVINL void gload_lds16(const bf16_t* g, bf16_t* l) {
  __builtin_amdgcn_global_load_lds(
      (__attribute__((address_space(1))) void*)(g),
      (__attribute__((address_space(3))) void*)(l), 16, 0, 0);
}

// ---------------------------------------------------------------------------
// cast fp32 -> bf16
// ---------------------------------------------------------------------------
__global__ __launch_bounds__(256) void cast_f32_bf16(
    const float* __restrict__ in, bf16_t* __restrict__ out, long n) {
  long i = ((long)blockIdx.x * 256 + threadIdx.x) * 4;
  if (i + 3 < n) {
    float4 v = *reinterpret_cast<const float4*>(in + i);
    bf16x4 o = { (bf16_t)v.x, (bf16_t)v.y, (bf16_t)v.z, (bf16_t)v.w };
    *reinterpret_cast<bf16x4*>(out + i) = o;
  }
}

// ---------------------------------------------------------------------------
// W [1024][3072] fp32 -> Wt [3072][1024] bf16
// ---------------------------------------------------------------------------
__global__ __launch_bounds__(256) void transpose_W(
    const float* __restrict__ W, bf16_t* __restrict__ Wt) {
  __shared__ bf16_t tile[64][66];
  const int c0 = blockIdx.x * 64, r0 = blockIdx.y * 64;
  const int tc = threadIdx.x & 63, tr = threadIdx.x >> 6;
#pragma unroll
  for (int k = 0; k < 16; ++k) {
    int rl = k * 4 + tr;
    tile[rl][tc] = (bf16_t)W[(size_t)(r0 + rl) * 3072 + c0 + tc];
  }
  __syncthreads();
#pragma unroll
  for (int k = 0; k < 16; ++k) {
    int cl = k * 4 + tr;
    Wt[(size_t)(c0 + cl) * 1024 + r0 + tc] = tile[tc][cl];
  }
}

// ---------------------------------------------------------------------------
// V slice of qkv -> Vt [b][h][n] bf16
// ---------------------------------------------------------------------------
__global__ __launch_bounds__(256) void transpose_V(
    const bf16_t* __restrict__ qkv, bf16_t* __restrict__ Vt) {
  __shared__ bf16_t tile[64][66];
  const int b = blockIdx.z;
  const int h0 = blockIdx.x * 64, n0 = blockIdx.y * 64;
  const int tc = threadIdx.x & 63, tr = threadIdx.x >> 6;
#pragma unroll
  for (int k = 0; k < 16; ++k) {
    int nl = k * 4 + tr;
    tile[nl][tc] = qkv[((size_t)b * 2048 + n0 + nl) * 3072 + 2048 + h0 + tc];
  }
  __syncthreads();
#pragma unroll
  for (int k = 0; k < 16; ++k) {
    int hl = k * 4 + tr;
    Vt[((size_t)b * 1024 + h0 + hl) * 2048 + n0 + tc] = tile[tc][hl];
  }
}

// ---------------------------------------------------------------------------
// gemm256: C[M][N] = A[M][K] @ B[N][K]^T, 256xBN tile, BK=64, 512 threads.
// 4 phases/K-tile; fragment ds_reads issued ONE PHASE EARLY (reg double-
// buffer afA/afB, bfrA/bfrB) so LDS service hides under MFMA cluster.
// vmcnt(4+IB) placed BEFORE the barrier preceding dependent reads (cross-
// wave staging visibility). T2 slot-swizzle (conflict-free, verified 0).
// EPI 0: bf16 out, (acc+bias[col])*(col<1024 ? 1/32 : 1);  EPI 1: fp32 out.
// ---------------------------------------------------------------------------
template <int BN, int EPI>
__global__ __launch_bounds__(512, 2) void gemm256(
    const bf16_t* __restrict__ A, const bf16_t* __restrict__ B,
    void* __restrict__ C, const float* __restrict__ bias,
    int K, int lda, int ldb, int ldc,
    long sA, long sB, long sC) {
  constexpr int WN = BN / 64;          // waves along N
  constexpr int WM = 8 / WN;           // waves along M
  constexpr int MR = (256 / WM) / 16;  // row frags per wave
  constexpr int MR2 = MR / 2;
  constexpr int IB = BN / 128;         // B gload instr/thread/half
  constexpr int HTE = (256 + BN) * 32; // elements per (buf, ks)

  __shared__ bf16_t lds[2][2][HTE];  // [buf][k-half][A 256x32 | B BNx32]

  // XCD-aware swizzle (nwg % 8 == 0 for all our grids)
  const int gx = gridDim.x, gy = gridDim.y;
  const int nwg = gx * gy * gridDim.z;
  const int flat = blockIdx.x + gx * (blockIdx.y + gy * blockIdx.z);
  const int swz = (flat & 7) * (nwg >> 3) + (flat >> 3);
  const int bx = swz % gx;
  const int rem = swz / gx;
  const int by = rem % gy, bz = rem / gy;

  const int m0 = by * 256, n0 = bx * BN;
  A += (size_t)bz * sA;
  B += (size_t)bz * sB;

  const int tid = threadIdx.x;
  const int w = tid >> 6, lane = tid & 63;
  const int wr = w / WN, wc = w % WN;

  // staging source: row = lane>>2, k-chunk = (lane&3)^((lane>>3)&3)  (T2)
  const int srow = lane >> 2;
  const int schunk = ((lane & 3) ^ ((lane >> 3) & 3)) * 8;
  const bf16_t* gA = A + (size_t)(m0 + w * 32 + srow) * lda + schunk;
  const bf16_t* gB = B + (size_t)(n0 + w * (IB == 2 ? 32 : 16) + srow) * ldb + schunk;

  auto stageA = [&](int t, int ks) {
    const bf16_t* g = gA + (size_t)t * 64 + ks * 32;
    bf16_t* l = &lds[t & 1][ks][(w * 32) * 32];
    gload_lds16(g, l);
    gload_lds16(g + (size_t)16 * lda, l + 16 * 32);
  };
  auto stageB = [&](int t, int ks) {
    const bf16_t* g = gB + (size_t)t * 64 + ks * 32;
    if constexpr (IB == 2) {
      bf16_t* l = &lds[t & 1][ks][256 * 32 + (w * 32) * 32];
      gload_lds16(g, l);
      gload_lds16(g + (size_t)16 * ldb, l + 16 * 32);
    } else {
      bf16_t* l = &lds[t & 1][ks][256 * 32 + (w * 16) * 32];
      gload_lds16(g, l);
    }
  };

  const int rsel = lane & 15, kg = lane >> 4;
  const int kswz = (kg ^ ((rsel >> 1) & 3)) * 8;  // T2 read-side XOR
  f32x4 acc[MR][4] = {};
  bf16x8 afA[MR2], afB[MR2], bfrA[4], bfrB[4];

  auto ldA = [&](int b, int ks, int fi) -> bf16x8 {
    return *reinterpret_cast<const bf16x8*>(
        &lds[b][ks][(wr * (MR * 16) + fi * 16 + rsel) * 32 + kswz]);
  };
  auto ldB = [&](int b, int ks, int fj) -> bf16x8 {
    return *reinterpret_cast<const bf16x8*>(
        &lds[b][ks][256 * 32 + (wc * 64 + fj * 16 + rsel) * 32 + kswz]);
  };

#define BAR __builtin_amdgcn_s_barrier()
#define VMW(N) asm volatile("s_waitcnt vmcnt(%0)" ::"n"(N) : "memory")
#define RD_A(AF, t, ks, hi)                                    \
  _Pragma("unroll") for (int i = 0; i < MR2; ++i)              \
      AF[i] = ldA((t) & 1, ks, (hi) * MR2 + i)
#define RD_B(BF, t, ks)                                        \
  _Pragma("unroll") for (int j = 0; j < 4; ++j)                \
      BF[j] = ldB((t) & 1, ks, j)
#define MM(BF, AF, hi)                                         \
  __builtin_amdgcn_s_setprio(1);                               \
  _Pragma("unroll") for (int i = 0; i < MR2; ++i)              \
      _Pragma("unroll") for (int j = 0; j < 4; ++j)            \
          acc[(hi) * MR2 + i][j] =                             \
      __builtin_amdgcn_mfma_f32_16x16x32_bf16(                 \
          AF[i], BF[j], acc[(hi) * MR2 + i][j], 0, 0, 0);      \
  __builtin_amdgcn_s_setprio(0)

  const int NT = K >> 6;

  // prologue: stage (0,0),(0,1),(1,0); confirm (0,*) staged; first reads
  stageA(0, 0); stageB(0, 0);
  stageA(0, 1); stageB(0, 1);
  stageA(1, 0); stageB(1, 0);
  VMW(4 + 2 * IB);
  BAR;
  RD_B(bfrA, 0, 0);
  RD_A(afA, 0, 0, 0);

  for (int t = 0; t < NT - 1; ++t) {
    // P1: MFMA(ks0,hi0) | reads for P2 issued first
    RD_A(afB, t, 0, 1);
    stageA(t + 1, 1);
    BAR;
    MM(bfrA, afA, 0);
    VMW(4 + IB);  // guards (t,ks1) staging, consumed after next barrier
    BAR;
    // P2: MFMA(ks0,hi1)
    RD_B(bfrB, t, 1);
    RD_A(afA, t, 1, 0);
    stageB(t + 1, 1);
    BAR;
    MM(bfrA, afB, 1);
    BAR;
    // P3: MFMA(ks1,hi0)
    RD_A(afB, t, 1, 1);
    if (t < NT - 2) stageA(t + 2, 0);
    BAR;
    MM(bfrB, afA, 0);
    VMW(4 + IB);  // guards (t+1,ks0) staging
    BAR;
    // P4: MFMA(ks1,hi1)
    RD_B(bfrA, t + 1, 0);
    RD_A(afA, t + 1, 0, 0);
    if (t < NT - 2) stageB(t + 2, 0);
    BAR;
    MM(bfrB, afB, 1);
    BAR;
  }
  // peeled last K-tile (no staging; drain)
  {
    const int t = NT - 1;
    RD_A(afB, t, 0, 1);
    BAR;
    MM(bfrA, afA, 0);
    VMW(0);
    BAR;
    RD_B(bfrB, t, 1);
    RD_A(afA, t, 1, 0);
    BAR;
    MM(bfrA, afB, 1);
    BAR;
    RD_A(afB, t, 1, 1);
    BAR;
    MM(bfrB, afA, 0);
    BAR;
    MM(bfrB, afB, 1);
  }
#undef BAR
#undef VMW
#undef RD_A
#undef RD_B
#undef MM

  // epilogue: C/D layout col=lane&15, row=(lane>>4)*4+reg (m89-verified)
  const int rb = (lane >> 4) * 4, cs = lane & 15;
#pragma unroll
  for (int i = 0; i < MR; ++i) {
#pragma unroll
    for (int j = 0; j < 4; ++j) {
#pragma unroll
      for (int r = 0; r < 4; ++r) {
        const int row = m0 + wr * (MR * 16) + i * 16 + rb + r;
        const int col = n0 + wc * 64 + j * 16 + cs;
        float v = acc[i][j][r];
        if constexpr (EPI == 0) {
          v = (v + bias[col]) * (col < 1024 ? 0.03125f : 1.0f);
          ((bf16_t*)C)[(size_t)bz * sC + (size_t)row * ldc + col] = (bf16_t)v;
        } else {
          ((float*)C)[(size_t)bz * sC + (size_t)row * ldc + col] = v;
        }
      }
    }
  }
}

// ---------------------------------------------------------------------------
// row softmax: S fp32 [8192 rows][2048] -> P bf16
// ---------------------------------------------------------------------------
__global__ __launch_bounds__(256) void softmax_k(
    const float* __restrict__ S, bf16_t* __restrict__ P) {
  const long row = blockIdx.x;
  const float* s = S + row * 2048;
  const int tid = threadIdx.x;
  const int wave = tid >> 6, lane = tid & 63;

  float v[8];
  {
    const float4* s4 = reinterpret_cast<const float4*>(s + tid * 8);
    float4 a = s4[0], b = s4[1];
    v[0] = a.x; v[1] = a.y; v[2] = a.z; v[3] = a.w;
    v[4] = b.x; v[5] = b.y; v[6] = b.z; v[7] = b.w;
  }
  float m = v[0];
#pragma unroll
  for (int k = 1; k < 8; ++k) m = fmaxf(m, v[k]);
#pragma unroll
  for (int off = 32; off; off >>= 1) m = fmaxf(m, __shfl_xor(m, off));

  __shared__ float red[8];
  if (lane == 0) red[wave] = m;
  __syncthreads();
  m = fmaxf(fmaxf(red[0], red[1]), fmaxf(red[2], red[3]));

  float e[8], sum = 0.f;
#pragma unroll
  for (int k = 0; k < 8; ++k) { e[k] = __expf(v[k] - m); sum += e[k]; }
#pragma unroll
  for (int off = 32; off; off >>= 1) sum += __shfl_xor(sum, off);
  if (lane == 0) red[4 + wave] = sum;
  __syncthreads();
  sum = red[4] + red[5] + red[6] + red[7];
  const float inv = 1.0f / sum;

  bf16x8 o;
#pragma unroll
  for (int k = 0; k < 8; ++k) o[k] = (bf16_t)(e[k] * inv);
  *reinterpret_cast<bf16x8*>(P + row * 2048 + tid * 8) = o;
}

// ---------------------------------------------------------------------------
// launch
// ---------------------------------------------------------------------------
extern "C" void kernel_launch(void* const* d_in, const int* in_sizes, int n_in,
                              void* d_out, int out_size, void* d_ws,
                              size_t ws_size, hipStream_t stream) {
  const float* x = (const float*)d_in[0];  // [4,2048,1024]
  const float* W = (const float*)d_in[1];  // [1024,3072]
  const float* b = (const float*)d_in[2];  // [3072]
  float* out = (float*)d_out;              // [4,2048,1024] fp32

  char* w = (char*)d_ws;
  bf16_t* xb = (bf16_t*)w;   w += (size_t)8192 * 1024 * 2;
  bf16_t* Wt = (bf16_t*)w;   w += (size_t)3072 * 1024 * 2;
  bf16_t* qkv = (bf16_t*)w;  w += (size_t)8192 * 3072 * 2;
  bf16_t* Vt = (bf16_t*)w;   w += (size_t)4 * 1024 * 2048 * 2;
  float* S = (float*)w;      w += (size_t)4 * 2048 * 2048 * 4;
  bf16_t* P = (bf16_t*)w;    w += (size_t)4 * 2048 * 2048 * 2;

  cast_f32_bf16<<<8192, 256, 0, stream>>>(x, xb, (long)8192 * 1024);
  transpose_W<<<dim3(48, 16), 256, 0, stream>>>(W, Wt);

  // qkv = x @ W + b (Q scaled by 1/32), bf16 out. BN=128, grid 24x32 = 768
  // = 3 exact CU rounds (no tail).
  gemm256<128, 0><<<dim3(24, 32, 1), 512, 0, stream>>>(
      xb, Wt, qkv, b, 1024, 1024, 1024, 3072, 0, 0, 0);

  transpose_V<<<dim3(16, 32, 4), 256, 0, stream>>>(qkv, Vt);

  // S = Qs @ K^T, fp32 out. grid 8x8x4 = 256 wgs
  gemm256<256, 1><<<dim3(8, 8, 4), 512, 0, stream>>>(
      qkv, qkv + 1024, S, nullptr, 1024, 3072, 3072, 2048,
      (long)2048 * 3072, (long)2048 * 3072, (long)2048 * 2048);

  softmax_k<<<8192, 256, 0, stream>>>(S, P);

  // out = P @ Vt^T, fp32 out. BN=128, grid 8x8x4 = 256 wgs
  gemm256<128, 1><<<dim3(8, 8, 4), 512, 0, stream>>>(
      P, Vt, out, nullptr, 2048, 2048, 2048, 1024,
      (long)2048 * 2048, (long)1024 * 2048, (long)2048 * 1024);
}

// Round 5
// 186.866 us; speedup vs baseline: 1.0116x; 1.0116x over previous
//
#include <hip/hip_runtime.h>
#include <hip/hip_bf16.h>
#include <cstdint>
#include <cstddef>

typedef __bf16 bf16_t;
typedef __bf16 bf16x8 __attribute__((ext_vector_type(8)));
typedef __bf16 bf16x4 __attribute__((ext_vector_type(4)));
typedef float f32x4 __attribute__((ext_vector_type(4)));

#define DEVINL __device__ __forceinline__

DEVINL void gload_lds16(const bf16_t* g, bf16_t* l) {
  __builtin_amdgcn_global_load_lds(
      (__attribute__((address_space(1))) void*)(g),
      (__attribute__((address_space(3))) void*)(l), 16, 0, 0);
}

// ---------------------------------------------------------------------------
// cast fp32 -> bf16
// ---------------------------------------------------------------------------
__global__ __launch_bounds__(256) void cast_f32_bf16(
    const float* __restrict__ in, bf16_t* __restrict__ out, long n) {
  long i = ((long)blockIdx.x * 256 + threadIdx.x) * 4;
  if (i + 3 < n) {
    float4 v = *reinterpret_cast<const float4*>(in + i);
    bf16x4 o = { (bf16_t)v.x, (bf16_t)v.y, (bf16_t)v.z, (bf16_t)v.w };
    *reinterpret_cast<bf16x4*>(out + i) = o;
  }
}

// ---------------------------------------------------------------------------
// W [1024][3072] fp32 -> Wt [3072][1024] bf16
// ---------------------------------------------------------------------------
__global__ __launch_bounds__(256) void transpose_W(
    const float* __restrict__ W, bf16_t* __restrict__ Wt) {
  __shared__ bf16_t tile[64][66];
  const int c0 = blockIdx.x * 64, r0 = blockIdx.y * 64;
  const int tc = threadIdx.x & 63, tr = threadIdx.x >> 6;
#pragma unroll
  for (int k = 0; k < 16; ++k) {
    int rl = k * 4 + tr;
    tile[rl][tc] = (bf16_t)W[(size_t)(r0 + rl) * 3072 + c0 + tc];
  }
  __syncthreads();
#pragma unroll
  for (int k = 0; k < 16; ++k) {
    int cl = k * 4 + tr;
    Wt[(size_t)(c0 + cl) * 1024 + r0 + tc] = tile[tc][cl];
  }
}

// ---------------------------------------------------------------------------
// V slice of qkv -> Vt [b][h][n] bf16
// ---------------------------------------------------------------------------
__global__ __launch_bounds__(256) void transpose_V(
    const bf16_t* __restrict__ qkv, bf16_t* __restrict__ Vt) {
  __shared__ bf16_t tile[64][66];
  const int b = blockIdx.z;
  const int h0 = blockIdx.x * 64, n0 = blockIdx.y * 64;
  const int tc = threadIdx.x & 63, tr = threadIdx.x >> 6;
#pragma unroll
  for (int k = 0; k < 16; ++k) {
    int nl = k * 4 + tr;
    tile[nl][tc] = qkv[((size_t)b * 2048 + n0 + nl) * 3072 + 2048 + h0 + tc];
  }
  __syncthreads();
#pragma unroll
  for (int k = 0; k < 16; ++k) {
    int hl = k * 4 + tr;
    Vt[((size_t)b * 1024 + h0 + hl) * 2048 + n0 + tc] = tile[tc][hl];
  }
}

// ---------------------------------------------------------------------------
// gemm256: C[M][N] = A[M][K] @ B[N][K]^T, 256xBN tile, BK=64, 512 threads.
// Faithful m201 8-phase port: 2 K-tiles per iteration (STATIC LDS buffer
// indices), in-phase ds_reads, per phase:
//   reads | 1 stage unit | BAR | lgkmcnt(0) | sched_barrier(0) |
//   setprio(1) 16xMFMA setprio(0) | [vmcnt(2+IB) at ph2/ph4] | BAR
// T2 slot-swizzle (verified conflict-free). vmcnt never 0 in steady loop.
// EPI 0: bf16 out, (acc+bias[col])*(col<1024 ? 1/32 : 1);  EPI 1: fp32 out.
// ---------------------------------------------------------------------------
template <int BN, int EPI>
__global__ __launch_bounds__(512, 2) void gemm256(
    const bf16_t* __restrict__ A, const bf16_t* __restrict__ B,
    void* __restrict__ C, const float* __restrict__ bias,
    int K, int lda, int ldb, int ldc,
    long sA, long sB, long sC) {
  constexpr int WN = BN / 64;          // waves along N
  constexpr int WM = 8 / WN;           // waves along M
  constexpr int MR = (256 / WM) / 16;  // row frags per wave
  constexpr int MR2 = MR / 2;
  constexpr int IB = BN / 128;         // B gloads per stage unit
  constexpr int HTE = (256 + BN) * 32; // elems per (buf, ks)

  __shared__ bf16_t lds[2][2][HTE];  // [buf][k-half][A 256x32 | B BNx32]

  // XCD-aware swizzle (nwg % 8 == 0 for all our grids)
  const int gx = gridDim.x, gy = gridDim.y;
  const int nwg = gx * gy * gridDim.z;
  const int flat = blockIdx.x + gx * (blockIdx.y + gy * blockIdx.z);
  const int swz = (flat & 7) * (nwg >> 3) + (flat >> 3);
  const int bx = swz % gx;
  const int rem = swz / gx;
  const int by = rem % gy, bz = rem / gy;

  const int m0 = by * 256, n0 = bx * BN;
  A += (size_t)bz * sA;
  B += (size_t)bz * sB;

  const int tid = threadIdx.x;
  const int w = tid >> 6, lane = tid & 63;
  const int wr = w / WN, wc = w % WN;

  // staging source: row = lane>>2, k-chunk = (lane&3)^((lane>>3)&3)  (T2)
  const int srow = lane >> 2;
  const int schunk = ((lane & 3) ^ ((lane >> 3) & 3)) * 8;
  const bf16_t* gA = A + (size_t)(m0 + w * 32 + srow) * lda + schunk;
  const bf16_t* gB = B + (size_t)(n0 + w * (IB == 2 ? 32 : 16) + srow) * ldb + schunk;

  const int rsel = lane & 15, kg = lane >> 4;
  const int kswz = (kg ^ ((rsel >> 1) & 3)) * 8;  // T2 read-side XOR
  f32x4 acc[MR][4] = {};
  bf16x8 af[MR2], bfr[4];

// stage unit A: 2 gloads (32 rows); stage unit B: IB gloads
#define SA(BUF, t, ks)                                                        \
  {                                                                           \
    const bf16_t* g = gA + (size_t)(t) * 64 + (ks) * 32;                      \
    bf16_t* l = &lds[BUF][ks][(w * 32) * 32];                                 \
    gload_lds16(g, l);                                                        \
    gload_lds16(g + (size_t)16 * lda, l + 16 * 32);                           \
  }
#define SB(BUF, t, ks)                                                        \
  {                                                                           \
    const bf16_t* g = gB + (size_t)(t) * 64 + (ks) * 32;                      \
    if constexpr (IB == 2) {                                                  \
      bf16_t* l = &lds[BUF][ks][256 * 32 + (w * 32) * 32];                    \
      gload_lds16(g, l);                                                      \
      gload_lds16(g + (size_t)16 * ldb, l + 16 * 32);                         \
    } else {                                                                  \
      bf16_t* l = &lds[BUF][ks][256 * 32 + (w * 16) * 32];                    \
      gload_lds16(g, l);                                                      \
    }                                                                         \
  }
#define RD_A(BUF, ks, hi)                                                     \
  _Pragma("unroll") for (int i = 0; i < MR2; ++i)                             \
      af[i] = *reinterpret_cast<const bf16x8*>(                               \
          &lds[BUF][ks][(wr * (MR * 16) + ((hi) * MR2 + i) * 16 + rsel) * 32  \
                        + kswz]);
#define RD_B(BUF, ks)                                                         \
  _Pragma("unroll") for (int j = 0; j < 4; ++j)                               \
      bfr[j] = *reinterpret_cast<const bf16x8*>(                              \
          &lds[BUF][ks][256 * 32 + (wc * 64 + j * 16 + rsel) * 32 + kswz]);
#define VMW(N) asm volatile("s_waitcnt vmcnt(%0)" ::"n"(N) : "memory")
#define BAR __builtin_amdgcn_s_barrier()
#define PH(BUF, ks, hi, STG, VM)                                              \
  {                                                                           \
    if ((hi) == 0) { RD_B(BUF, ks); }                                         \
    RD_A(BUF, ks, hi);                                                        \
    STG;                                                                      \
    BAR;                                                                      \
    asm volatile("s_waitcnt lgkmcnt(0)" ::: "memory");                        \
    __builtin_amdgcn_sched_barrier(0);                                        \
    __builtin_amdgcn_s_setprio(1);                                            \
    _Pragma("unroll") for (int i = 0; i < MR2; ++i)                           \
        _Pragma("unroll") for (int j = 0; j < 4; ++j)                         \
            acc[(hi) * MR2 + i][j] =                                          \
        __builtin_amdgcn_mfma_f32_16x16x32_bf16(                              \
            af[i], bfr[j], acc[(hi) * MR2 + i][j], 0, 0, 0);                  \
    __builtin_amdgcn_s_setprio(0);                                            \
    VM;                                                                       \
    BAR;                                                                      \
  }

  const int NT = K >> 6;  // 16 or 32: even, >= 4

  // prologue: stage tile 0 -> buf0, drain once
  SA(0, 0, 0); SB(0, 0, 0);
  SA(0, 0, 1); SB(0, 0, 1);
  VMW(0);
  BAR;

  int t = 0;
  for (; t + 2 < NT; t += 2) {
    // K-tile t on buf0, stage t+1 -> buf1
    PH(0, 0, 0, SA(1, t + 1, 0), );
    PH(0, 0, 1, SB(1, t + 1, 0), VMW(2 + IB));
    PH(0, 1, 0, SA(1, t + 1, 1), );
    PH(0, 1, 1, SB(1, t + 1, 1), VMW(2 + IB));
    // K-tile t+1 on buf1, stage t+2 -> buf0
    PH(1, 0, 0, SA(0, t + 2, 0), );
    PH(1, 0, 1, SB(0, t + 2, 0), VMW(2 + IB));
    PH(1, 1, 0, SA(0, t + 2, 1), );
    PH(1, 1, 1, SB(0, t + 2, 1), VMW(2 + IB));
  }
  // peeled last two K-tiles (t = NT-2): stage only t+1
  PH(0, 0, 0, SA(1, t + 1, 0), );
  PH(0, 0, 1, SB(1, t + 1, 0), VMW(2 + IB));
  PH(0, 1, 0, SA(1, t + 1, 1), );
  PH(0, 1, 1, SB(1, t + 1, 1), VMW(0));
  PH(1, 0, 0, , );
  PH(1, 0, 1, , );
  PH(1, 1, 0, , );
  PH(1, 1, 1, , );

#undef SA
#undef SB
#undef RD_A
#undef RD_B
#undef VMW
#undef BAR
#undef PH

  // epilogue: C/D layout col=lane&15, row=(lane>>4)*4+reg (m89-verified)
  const int rb = (lane >> 4) * 4, cs = lane & 15;
#pragma unroll
  for (int i = 0; i < MR; ++i) {
#pragma unroll
    for (int j = 0; j < 4; ++j) {
#pragma unroll
      for (int r = 0; r < 4; ++r) {
        const int row = m0 + wr * (MR * 16) + i * 16 + rb + r;
        const int col = n0 + wc * 64 + j * 16 + cs;
        float v = acc[i][j][r];
        if constexpr (EPI == 0) {
          v = (v + bias[col]) * (col < 1024 ? 0.03125f : 1.0f);
          ((bf16_t*)C)[(size_t)bz * sC + (size_t)row * ldc + col] = (bf16_t)v;
        } else {
          ((float*)C)[(size_t)bz * sC + (size_t)row * ldc + col] = v;
        }
      }
    }
  }
}

// ---------------------------------------------------------------------------
// row softmax: S fp32 [8192 rows][2048] -> P bf16
// ---------------------------------------------------------------------------
__global__ __launch_bounds__(256) void softmax_k(
    const float* __restrict__ S, bf16_t* __restrict__ P) {
  const long row = blockIdx.x;
  const float* s = S + row * 2048;
  const int tid = threadIdx.x;
  const int wave = tid >> 6, lane = tid & 63;

  float v[8];
  {
    const float4* s4 = reinterpret_cast<const float4*>(s + tid * 8);
    float4 a = s4[0], b = s4[1];
    v[0] = a.x; v[1] = a.y; v[2] = a.z; v[3] = a.w;
    v[4] = b.x; v[5] = b.y; v[6] = b.z; v[7] = b.w;
  }
  float m = v[0];
#pragma unroll
  for (int k = 1; k < 8; ++k) m = fmaxf(m, v[k]);
#pragma unroll
  for (int off = 32; off; off >>= 1) m = fmaxf(m, __shfl_xor(m, off));

  __shared__ float red[8];
  if (lane == 0) red[wave] = m;
  __syncthreads();
  m = fmaxf(fmaxf(red[0], red[1]), fmaxf(red[2], red[3]));

  float e[8], sum = 0.f;
#pragma unroll
  for (int k = 0; k < 8; ++k) { e[k] = __expf(v[k] - m); sum += e[k]; }
#pragma unroll
  for (int off = 32; off; off >>= 1) sum += __shfl_xor(sum, off);
  if (lane == 0) red[4 + wave] = sum;
  __syncthreads();
  sum = red[4] + red[5] + red[6] + red[7];
  const float inv = 1.0f / sum;

  bf16x8 o;
#pragma unroll
  for (int k = 0; k < 8; ++k) o[k] = (bf16_t)(e[k] * inv);
  *reinterpret_cast<bf16x8*>(P + row * 2048 + tid * 8) = o;
}

// ---------------------------------------------------------------------------
// launch
// ---------------------------------------------------------------------------
extern "C" void kernel_launch(void* const* d_in, const int* in_sizes, int n_in,
                              void* d_out, int out_size, void* d_ws,
                              size_t ws_size, hipStream_t stream) {
  const float* x = (const float*)d_in[0];  // [4,2048,1024]
  const float* W = (const float*)d_in[1];  // [1024,3072]
  const float* b = (const float*)d_in[2];  // [3072]
  float* out = (float*)d_out;              // [4,2048,1024] fp32

  char* w = (char*)d_ws;
  bf16_t* xb = (bf16_t*)w;   w += (size_t)8192 * 1024 * 2;
  bf16_t* Wt = (bf16_t*)w;   w += (size_t)3072 * 1024 * 2;
  bf16_t* qkv = (bf16_t*)w;  w += (size_t)8192 * 3072 * 2;
  bf16_t* Vt = (bf16_t*)w;   w += (size_t)4 * 1024 * 2048 * 2;
  float* S = (float*)w;      w += (size_t)4 * 2048 * 2048 * 4;
  bf16_t* P = (bf16_t*)w;    w += (size_t)4 * 2048 * 2048 * 2;

  cast_f32_bf16<<<8192, 256, 0, stream>>>(x, xb, (long)8192 * 1024);
  transpose_W<<<dim3(48, 16), 256, 0, stream>>>(W, Wt);

  // qkv = x @ W + b (Q scaled by 1/32), bf16 out. BN=128, grid 24x32 = 768
  gemm256<128, 0><<<dim3(24, 32, 1), 512, 0, stream>>>(
      xb, Wt, qkv, b, 1024, 1024, 1024, 3072, 0, 0, 0);

  transpose_V<<<dim3(16, 32, 4), 256, 0, stream>>>(qkv, Vt);

  // S = Qs @ K^T, fp32 out. grid 8x8x4 = 256 wgs
  gemm256<256, 1><<<dim3(8, 8, 4), 512, 0, stream>>>(
      qkv, qkv + 1024, S, nullptr, 1024, 3072, 3072, 2048,
      (long)2048 * 3072, (long)2048 * 3072, (long)2048 * 2048);

  softmax_k<<<8192, 256, 0, stream>>>(S, P);

  // out = P @ Vt^T, fp32 out. BN=128, grid 8x8x4 = 256 wgs
  gemm256<128, 1><<<dim3(8, 8, 4), 512, 0, stream>>>(
      P, Vt, out, nullptr, 2048, 2048, 2048, 1024,
      (long)2048 * 2048, (long)1024 * 2048, (long)2048 * 1024);
}

// Round 6
// 185.997 us; speedup vs baseline: 1.0163x; 1.0047x over previous
//
#include <hip/hip_runtime.h>
#include <hip/hip_bf16.h>
#include <cstdint>
#include <cstddef>

typedef __bf16 bf16_t;
typedef __bf16 bf16x8 __attribute__((ext_vector_type(8)));
typedef __bf16 bf16x4 __attribute__((ext_vector_type(4)));
typedef float f32x4 __attribute__((ext_vector_type(4)));

#define DEVINL __device__ __forceinline__

DEVINL void gload_lds16(const bf16_t* g, bf16_t* l) {
  __builtin_amdgcn_global_load_lds(
      (__attribute__((address_space(1))) void*)(g),
      (__attribute__((address_space(3))) void*)(l), 16, 0, 0);
}

// ---------------------------------------------------------------------------
// cast fp32 -> bf16
// ---------------------------------------------------------------------------
__global__ __launch_bounds__(256) void cast_f32_bf16(
    const float* __restrict__ in, bf16_t* __restrict__ out, long n) {
  long i = ((long)blockIdx.x * 256 + threadIdx.x) * 4;
  if (i + 3 < n) {
    float4 v = *reinterpret_cast<const float4*>(in + i);
    bf16x4 o = { (bf16_t)v.x, (bf16_t)v.y, (bf16_t)v.z, (bf16_t)v.w };
    *reinterpret_cast<bf16x4*>(out + i) = o;
  }
}

// ---------------------------------------------------------------------------
// W [1024][3072] fp32 -> Wt [3072][1024] bf16
// ---------------------------------------------------------------------------
__global__ __launch_bounds__(256) void transpose_W(
    const float* __restrict__ W, bf16_t* __restrict__ Wt) {
  __shared__ bf16_t tile[64][66];
  const int c0 = blockIdx.x * 64, r0 = blockIdx.y * 64;
  const int tc = threadIdx.x & 63, tr = threadIdx.x >> 6;
#pragma unroll
  for (int k = 0; k < 16; ++k) {
    int rl = k * 4 + tr;
    tile[rl][tc] = (bf16_t)W[(size_t)(r0 + rl) * 3072 + c0 + tc];
  }
  __syncthreads();
#pragma unroll
  for (int k = 0; k < 16; ++k) {
    int cl = k * 4 + tr;
    Wt[(size_t)(c0 + cl) * 1024 + r0 + tc] = tile[tc][cl];
  }
}

// ---------------------------------------------------------------------------
// dense V [8192][1024] -> Vt [b][h][n] bf16
// ---------------------------------------------------------------------------
__global__ __launch_bounds__(256) void transpose_V(
    const bf16_t* __restrict__ V, bf16_t* __restrict__ Vt) {
  __shared__ bf16_t tile[64][66];
  const int b = blockIdx.z;
  const int h0 = blockIdx.x * 64, n0 = blockIdx.y * 64;
  const int tc = threadIdx.x & 63, tr = threadIdx.x >> 6;
#pragma unroll
  for (int k = 0; k < 16; ++k) {
    int nl = k * 4 + tr;
    tile[nl][tc] = V[((size_t)b * 2048 + n0 + nl) * 1024 + h0 + tc];
  }
  __syncthreads();
#pragma unroll
  for (int k = 0; k < 16; ++k) {
    int hl = k * 4 + tr;
    Vt[((size_t)b * 1024 + h0 + hl) * 2048 + n0 + tc] = tile[tc][hl];
  }
}

// ---------------------------------------------------------------------------
// gemm256: C[M][N] = A[M][K] @ B[N][K]^T, 256xBN tile, BK=64, 512 threads.
// 8-phase / 2 K-tiles, static LDS bufs, T2 slot-swizzle (conflict-free).
// DEEP staging: while reading slot q, stage slot q+3 (of 4 half-K-tile
// slots) -> every gload has 5-6 phases of slack; steady vmcnt(4+2*IB)
// (Little's-law fix: double in-flight bytes vs 2-ahead schedule).
// EPI 0: bf16 out into dense Q|K|V segments (seg = n0>>10, each 8192x1024,
//        ldc 1024), Q scaled 1/32.   EPI 1: fp32 out, ldc as passed.
// ---------------------------------------------------------------------------
template <int BN, int EPI>
__global__ __launch_bounds__(512, 2) void gemm256(
    const bf16_t* __restrict__ A, const bf16_t* __restrict__ B,
    void* __restrict__ C, const float* __restrict__ bias,
    int K, int lda, int ldb, int ldc,
    long sA, long sB, long sC) {
  constexpr int WN = BN / 64;          // waves along N
  constexpr int WM = 8 / WN;           // waves along M
  constexpr int MR = (256 / WM) / 16;  // row frags per wave
  constexpr int MR2 = MR / 2;
  constexpr int IB = BN / 128;         // B gloads per stage unit
  constexpr int HTE = (256 + BN) * 32; // elems per (buf, ks)

  __shared__ bf16_t lds[2][2][HTE];  // [buf][k-half][A 256x32 | B BNx32]

  // XCD-aware swizzle (nwg % 8 == 0 for all our grids)
  const int gx = gridDim.x, gy = gridDim.y;
  const int nwg = gx * gy * gridDim.z;
  const int flat = blockIdx.x + gx * (blockIdx.y + gy * blockIdx.z);
  const int swz = (flat & 7) * (nwg >> 3) + (flat >> 3);
  const int bx = swz % gx;
  const int rem = swz / gx;
  const int by = rem % gy, bz = rem / gy;

  const int m0 = by * 256, n0 = bx * BN;
  A += (size_t)bz * sA;
  B += (size_t)bz * sB;

  const int tid = threadIdx.x;
  const int w = tid >> 6, lane = tid & 63;
  const int wr = w / WN, wc = w % WN;

  // staging source: row = lane>>2, k-chunk = (lane&3)^((lane>>3)&3)  (T2)
  const int srow = lane >> 2;
  const int schunk = ((lane & 3) ^ ((lane >> 3) & 3)) * 8;
  const bf16_t* gA = A + (size_t)(m0 + w * 32 + srow) * lda + schunk;
  const bf16_t* gB = B + (size_t)(n0 + w * (IB == 2 ? 32 : 16) + srow) * ldb + schunk;

  const int rsel = lane & 15, kg = lane >> 4;
  const int kswz = (kg ^ ((rsel >> 1) & 3)) * 8;  // T2 read-side XOR
  f32x4 acc[MR][4] = {};
  bf16x8 af[MR2], bfr[4];

// stage unit A: 2 gloads (32 rows); stage unit B: IB gloads
#define SA(BUF, t, ks)                                                        \
  {                                                                           \
    const bf16_t* g = gA + (size_t)(t) * 64 + (ks) * 32;                      \
    bf16_t* l = &lds[BUF][ks][(w * 32) * 32];                                 \
    gload_lds16(g, l);                                                        \
    gload_lds16(g + (size_t)16 * lda, l + 16 * 32);                           \
  }
#define SB(BUF, t, ks)                                                        \
  {                                                                           \
    const bf16_t* g = gB + (size_t)(t) * 64 + (ks) * 32;                      \
    if constexpr (IB == 2) {                                                  \
      bf16_t* l = &lds[BUF][ks][256 * 32 + (w * 32) * 32];                    \
      gload_lds16(g, l);                                                      \
      gload_lds16(g + (size_t)16 * ldb, l + 16 * 32);                         \
    } else {                                                                  \
      bf16_t* l = &lds[BUF][ks][256 * 32 + (w * 16) * 32];                    \
      gload_lds16(g, l);                                                      \
    }                                                                         \
  }
#define RD_A(BUF, ks, hi)                                                     \
  _Pragma("unroll") for (int i = 0; i < MR2; ++i)                             \
      af[i] = *reinterpret_cast<const bf16x8*>(                               \
          &lds[BUF][ks][(wr * (MR * 16) + ((hi) * MR2 + i) * 16 + rsel) * 32  \
                        + kswz]);
#define RD_B(BUF, ks)                                                         \
  _Pragma("unroll") for (int j = 0; j < 4; ++j)                               \
      bfr[j] = *reinterpret_cast<const bf16x8*>(                              \
          &lds[BUF][ks][256 * 32 + (wc * 64 + j * 16 + rsel) * 32 + kswz]);
#define VMW(N) asm volatile("s_waitcnt vmcnt(%0)" ::"n"(N) : "memory")
#define BAR __builtin_amdgcn_s_barrier()
#define PH(BUF, ks, hi, STG, VM)                                              \
  {                                                                           \
    if ((hi) == 0) { RD_B(BUF, ks); }                                         \
    RD_A(BUF, ks, hi);                                                        \
    STG;                                                                      \
    BAR;                                                                      \
    asm volatile("s_waitcnt lgkmcnt(0)" ::: "memory");                        \
    __builtin_amdgcn_sched_barrier(0);                                        \
    __builtin_amdgcn_s_setprio(1);                                            \
    _Pragma("unroll") for (int i = 0; i < MR2; ++i)                           \
        _Pragma("unroll") for (int j = 0; j < 4; ++j)                         \
            acc[(hi) * MR2 + i][j] =                                          \
        __builtin_amdgcn_mfma_f32_16x16x32_bf16(                              \
            af[i], bfr[j], acc[(hi) * MR2 + i][j], 0, 0, 0);                  \
    __builtin_amdgcn_s_setprio(0);                                            \
    VM;                                                                       \
    BAR;                                                                      \
  }

  const int NT = K >> 6;  // 16 or 32: even, >= 4

  // prologue: stage slots (0,ks0),(0,ks1),(1,ks0); drain once
  SA(0, 0, 0); SB(0, 0, 0);
  SA(0, 0, 1); SB(0, 0, 1);
  SA(1, 1, 0); SB(1, 1, 0);
  VMW(0);
  BAR;

  // full tiles 0..NT-3 (2 per iteration; NT even).
  // tile t reads slots (t,ks0),(t,ks1); stages (t+1,ks1) at ph1/2 and
  // (t+2,ks0) at ph3/4  (3-slot-ahead queue).
  int t = 0;
  for (; t + 3 < NT; t += 2) {
    // K-tile t (buf0)
    PH(0, 0, 0, SA(1, t + 1, 1), );
    PH(0, 0, 1, SB(1, t + 1, 1), VMW(4 + 2 * IB));
    PH(0, 1, 0, SA(0, t + 2, 0), );
    PH(0, 1, 1, SB(0, t + 2, 0), VMW(4 + 2 * IB));
    // K-tile t+1 (buf1)
    PH(1, 0, 0, SA(0, t + 2, 1), );
    PH(1, 0, 1, SB(0, t + 2, 1), VMW(4 + 2 * IB));
    PH(1, 1, 0, SA(1, t + 3, 0), );
    PH(1, 1, 1, SB(1, t + 3, 0), VMW(4 + 2 * IB));
  }
  // peel tile NT-2 (buf0): stage only (NT-1,ks1)
  PH(0, 0, 0, SA(1, t + 1, 1), );
  PH(0, 0, 1, SB(1, t + 1, 1), VMW(4 + 2 * IB));
  PH(0, 1, 0, , );
  PH(0, 1, 1, , VMW(2 + IB));
  // peel tile NT-1 (buf1): no staging
  PH(1, 0, 0, , );
  PH(1, 0, 1, , VMW(0));
  PH(1, 1, 0, , );
  PH(1, 1, 1, , );

#undef SA
#undef SB
#undef RD_A
#undef RD_B
#undef VMW
#undef BAR
#undef PH

  // epilogue: C/D layout col=lane&15, row=(lane>>4)*4+reg (m89-verified)
  const int rb = (lane >> 4) * 4, cs = lane & 15;
#pragma unroll
  for (int i = 0; i < MR; ++i) {
#pragma unroll
    for (int j = 0; j < 4; ++j) {
#pragma unroll
      for (int r = 0; r < 4; ++r) {
        const int row = m0 + wr * (MR * 16) + i * 16 + rb + r;
        const int col = n0 + wc * 64 + j * 16 + cs;
        float v = acc[i][j][r];
        if constexpr (EPI == 0) {
          // dense Q|K|V segments; BN=128 keeps whole block in one segment
          const int seg = n0 >> 10;
          bf16_t* Cb = (bf16_t*)C + (size_t)seg * 8192 * 1024;
          const float scl = (seg == 0) ? 0.03125f : 1.0f;
          v = (v + bias[col]) * scl;
          Cb[(size_t)row * 1024 + (col & 1023)] = (bf16_t)v;
        } else {
          ((float*)C)[(size_t)bz * sC + (size_t)row * ldc + col] = v;
        }
      }
    }
  }
}

// ---------------------------------------------------------------------------
// row softmax: S fp32 [8192 rows][2048] -> P bf16
// ---------------------------------------------------------------------------
__global__ __launch_bounds__(256) void softmax_k(
    const float* __restrict__ S, bf16_t* __restrict__ P) {
  const long row = blockIdx.x;
  const float* s = S + row * 2048;
  const int tid = threadIdx.x;
  const int wave = tid >> 6, lane = tid & 63;

  float v[8];
  {
    const float4* s4 = reinterpret_cast<const float4*>(s + tid * 8);
    float4 a = s4[0], b = s4[1];
    v[0] = a.x; v[1] = a.y; v[2] = a.z; v[3] = a.w;
    v[4] = b.x; v[5] = b.y; v[6] = b.z; v[7] = b.w;
  }
  float m = v[0];
#pragma unroll
  for (int k = 1; k < 8; ++k) m = fmaxf(m, v[k]);
#pragma unroll
  for (int off = 32; off; off >>= 1) m = fmaxf(m, __shfl_xor(m, off));

  __shared__ float red[8];
  if (lane == 0) red[wave] = m;
  __syncthreads();
  m = fmaxf(fmaxf(red[0], red[1]), fmaxf(red[2], red[3]));

  float e[8], sum = 0.f;
#pragma unroll
  for (int k = 0; k < 8; ++k) { e[k] = __expf(v[k] - m); sum += e[k]; }
#pragma unroll
  for (int off = 32; off; off >>= 1) sum += __shfl_xor(sum, off);
  if (lane == 0) red[4 + wave] = sum;
  __syncthreads();
  sum = red[4] + red[5] + red[6] + red[7];
  const float inv = 1.0f / sum;

  bf16x8 o;
#pragma unroll
  for (int k = 0; k < 8; ++k) o[k] = (bf16_t)(e[k] * inv);
  *reinterpret_cast<bf16x8*>(P + row * 2048 + tid * 8) = o;
}

// ---------------------------------------------------------------------------
// launch
// ---------------------------------------------------------------------------
extern "C" void kernel_launch(void* const* d_in, const int* in_sizes, int n_in,
                              void* d_out, int out_size, void* d_ws,
                              size_t ws_size, hipStream_t stream) {
  const float* x = (const float*)d_in[0];  // [4,2048,1024]
  const float* W = (const float*)d_in[1];  // [1024,3072]
  const float* b = (const float*)d_in[2];  // [3072]
  float* out = (float*)d_out;              // [4,2048,1024] fp32

  char* w = (char*)d_ws;
  bf16_t* xb = (bf16_t*)w;   w += (size_t)8192 * 1024 * 2;
  bf16_t* Wt = (bf16_t*)w;   w += (size_t)3072 * 1024 * 2;
  bf16_t* QKV = (bf16_t*)w;  w += (size_t)3 * 8192 * 1024 * 2;  // dense Q,K,V
  bf16_t* Vt = (bf16_t*)w;   w += (size_t)4 * 1024 * 2048 * 2;
  float* S = (float*)w;      w += (size_t)4 * 2048 * 2048 * 4;
  bf16_t* P = (bf16_t*)w;    w += (size_t)4 * 2048 * 2048 * 2;

  bf16_t* Q = QKV;
  bf16_t* Kd = QKV + (size_t)8192 * 1024;
  bf16_t* V = QKV + (size_t)2 * 8192 * 1024;

  cast_f32_bf16<<<8192, 256, 0, stream>>>(x, xb, (long)8192 * 1024);
  transpose_W<<<dim3(48, 16), 256, 0, stream>>>(W, Wt);

  // Q|K|V dense = x @ W + b (Q scaled by 1/32). BN=128, grid 24x32 = 768
  gemm256<128, 0><<<dim3(24, 32, 1), 512, 0, stream>>>(
      xb, Wt, QKV, b, 1024, 1024, 1024, 1024, 0, 0, 0);

  transpose_V<<<dim3(16, 32, 4), 256, 0, stream>>>(V, Vt);

  // S = Qs @ K^T, fp32 out, dense operands. grid 8x8x4 = 256 wgs
  gemm256<256, 1><<<dim3(8, 8, 4), 512, 0, stream>>>(
      Q, Kd, S, nullptr, 1024, 1024, 1024, 2048,
      (long)2048 * 1024, (long)2048 * 1024, (long)2048 * 2048);

  softmax_k<<<8192, 256, 0, stream>>>(S, P);

  // out = P @ Vt^T, fp32 out. BN=128, grid 8x8x4 = 256 wgs
  gemm256<128, 1><<<dim3(8, 8, 4), 512, 0, stream>>>(
      P, Vt, out, nullptr, 2048, 2048, 2048, 1024,
      (long)2048 * 2048, (long)1024 * 2048, (long)2048 * 1024);
}

// Round 7
// 182.388 us; speedup vs baseline: 1.0364x; 1.0198x over previous
//
#include <hip/hip_runtime.h>
#include <hip/hip_bf16.h>
#include <cstdint>
#include <cstddef>

typedef __bf16 bf16_t;
typedef __bf16 bf16x8 __attribute__((ext_vector_type(8)));
typedef __bf16 bf16x4 __attribute__((ext_vector_type(4)));
typedef float f32x4 __attribute__((ext_vector_type(4)));
typedef _Float16 f16x8 __attribute__((ext_vector_type(8)));

#define DEVINL __device__ __forceinline__

DEVINL void gload_lds16(const bf16_t* g, bf16_t* l) {
  __builtin_amdgcn_global_load_lds(
      (__attribute__((address_space(1))) void*)(g),
      (__attribute__((address_space(3))) void*)(l), 16, 0, 0);
}

// ---------------------------------------------------------------------------
// cast fp32 -> bf16
// ---------------------------------------------------------------------------
__global__ __launch_bounds__(256) void cast_f32_bf16(
    const float* __restrict__ in, bf16_t* __restrict__ out, long n) {
  long i = ((long)blockIdx.x * 256 + threadIdx.x) * 4;
  if (i + 3 < n) {
    float4 v = *reinterpret_cast<const float4*>(in + i);
    bf16x4 o = { (bf16_t)v.x, (bf16_t)v.y, (bf16_t)v.z, (bf16_t)v.w };
    *reinterpret_cast<bf16x4*>(out + i) = o;
  }
}

// ---------------------------------------------------------------------------
// W [1024][3072] fp32 -> Wt [3072][1024] bf16
// ---------------------------------------------------------------------------
__global__ __launch_bounds__(256) void transpose_W(
    const float* __restrict__ W, bf16_t* __restrict__ Wt) {
  __shared__ bf16_t tile[64][66];
  const int c0 = blockIdx.x * 64, r0 = blockIdx.y * 64;
  const int tc = threadIdx.x & 63, tr = threadIdx.x >> 6;
#pragma unroll
  for (int k = 0; k < 16; ++k) {
    int rl = k * 4 + tr;
    tile[rl][tc] = (bf16_t)W[(size_t)(r0 + rl) * 3072 + c0 + tc];
  }
  __syncthreads();
#pragma unroll
  for (int k = 0; k < 16; ++k) {
    int cl = k * 4 + tr;
    Wt[(size_t)(c0 + cl) * 1024 + r0 + tc] = tile[tc][cl];
  }
}

// ---------------------------------------------------------------------------
// dense V [8192][1024] -> Vt [b][h][n] bf16
// ---------------------------------------------------------------------------
__global__ __launch_bounds__(256) void transpose_V(
    const bf16_t* __restrict__ V, bf16_t* __restrict__ Vt) {
  __shared__ bf16_t tile[64][66];
  const int b = blockIdx.z;
  const int h0 = blockIdx.x * 64, n0 = blockIdx.y * 64;
  const int tc = threadIdx.x & 63, tr = threadIdx.x >> 6;
#pragma unroll
  for (int k = 0; k < 16; ++k) {
    int nl = k * 4 + tr;
    tile[nl][tc] = V[((size_t)b * 2048 + n0 + nl) * 1024 + h0 + tc];
  }
  __syncthreads();
#pragma unroll
  for (int k = 0; k < 16; ++k) {
    int hl = k * 4 + tr;
    Vt[((size_t)b * 1024 + h0 + hl) * 2048 + n0 + tc] = tile[tc][hl];
  }
}

// ---------------------------------------------------------------------------
// gemm128: C[M][N] = A[M][K] @ B[N][K]^T. 128x128 tile, 4 waves (2x2),
// BK=32 phases, 3 LDS slots (48 KB -> 3 blocks/CU co-resident: the overlap
// mechanism). Per phase: 8 ds_read_b128 (T2-swizzled, conflict-free) |
// 4 gload_lds (2-slot-ahead) | 16 MFMA (compiler-counted lgkm interleave) |
// lgkmcnt(0) | vmcnt(4) | 1 barrier.  Full unroll via template NQ = K/32.
// EPI 0: bf16 dense Q|K|V segs (seg=n0>>10, Q scaled 1/32, +bias)
// EPI 1: fp32 out.   EPI 2: fp16 out.
// ---------------------------------------------------------------------------
template <int EPI, int NQ>
__global__ __launch_bounds__(256, 2) void gemm128(
    const bf16_t* __restrict__ A, const bf16_t* __restrict__ B,
    void* __restrict__ C, const float* __restrict__ bias,
    int lda, int ldb, int ldc, long sA, long sB, long sC) {
  __shared__ bf16_t lds[3][256 * 32];  // slot: A 128x32 | B 128x32

  // XCD-aware swizzle (nwg % 8 == 0 for all our grids)
  const int gx = gridDim.x, gy = gridDim.y;
  const int nwg = gx * gy * gridDim.z;
  const int flat = blockIdx.x + gx * (blockIdx.y + gy * blockIdx.z);
  const int swz = (flat & 7) * (nwg >> 3) + (flat >> 3);
  const int bx = swz % gx;
  const int rem = swz / gx;
  const int by = rem % gy, bz = rem / gy;

  const int m0 = by * 128, n0 = bx * 128;
  A += (size_t)bz * sA;
  B += (size_t)bz * sB;

  const int tid = threadIdx.x;
  const int w = tid >> 6, lane = tid & 63;
  const int wr = w >> 1, wc = w & 1;

  // staging source: row = lane>>2, k-chunk = (lane&3)^((lane>>3)&3)  (T2)
  const int srow = lane >> 2;
  const int schunk = ((lane & 3) ^ ((lane >> 3) & 3)) * 8;
  const bf16_t* gA = A + (size_t)(m0 + w * 32 + srow) * lda + schunk;
  const bf16_t* gB = B + (size_t)(n0 + w * 32 + srow) * ldb + schunk;

  const int rsel = lane & 15, kg = lane >> 4;
  const int kswz = (kg ^ ((rsel >> 1) & 3)) * 8;  // T2 read-side XOR
  f32x4 acc[4][4] = {};

#define SA(S, q)                                                              \
  {                                                                           \
    const bf16_t* g = gA + (size_t)(q) * 32;                                  \
    bf16_t* l = &lds[S][(w * 32) * 32];                                       \
    gload_lds16(g, l);                                                        \
    gload_lds16(g + (size_t)16 * lda, l + 16 * 32);                           \
  }
#define SB(S, q)                                                              \
  {                                                                           \
    const bf16_t* g = gB + (size_t)(q) * 32;                                  \
    bf16_t* l = &lds[S][128 * 32 + (w * 32) * 32];                            \
    gload_lds16(g, l);                                                        \
    gload_lds16(g + (size_t)16 * ldb, l + 16 * 32);                           \
  }
#define VMW(N) asm volatile("s_waitcnt vmcnt(%0)" ::"n"(N) : "memory")
#define LKW asm volatile("s_waitcnt lgkmcnt(0)" ::: "memory")
#define BAR __builtin_amdgcn_s_barrier()

  // prologue: stage slots 0,1; complete slot 0
  SA(0, 0); SB(0, 0);
  SA(1, 1); SB(1, 1);
  VMW(4);
  BAR;

#pragma unroll
  for (int q = 0; q < NQ; ++q) {
    const int s = q % 3;
    bf16x8 af[4], bfr[4];
#pragma unroll
    for (int j = 0; j < 4; ++j)
      bfr[j] = *reinterpret_cast<const bf16x8*>(
          &lds[s][128 * 32 + (wc * 64 + j * 16 + rsel) * 32 + kswz]);
#pragma unroll
    for (int i = 0; i < 4; ++i)
      af[i] = *reinterpret_cast<const bf16x8*>(
          &lds[s][(wr * 64 + i * 16 + rsel) * 32 + kswz]);
    if (q + 2 < NQ) {
      const int s2 = (q + 2) % 3;
      SA(s2, q + 2);
      SB(s2, q + 2);
    }
    __builtin_amdgcn_s_setprio(1);
#pragma unroll
    for (int i = 0; i < 4; ++i)
#pragma unroll
      for (int j = 0; j < 4; ++j)
        acc[i][j] = __builtin_amdgcn_mfma_f32_16x16x32_bf16(
            af[i], bfr[j], acc[i][j], 0, 0, 0);
    __builtin_amdgcn_s_setprio(0);
    if (q + 1 < NQ) {
      LKW;  // reads of slot s drained before BAR (WAR vs next-phase stage)
      if (q + 2 < NQ) VMW(4); else VMW(0);
      BAR;
    }
  }
#undef SA
#undef SB
#undef VMW
#undef LKW
#undef BAR

  // epilogue: C/D layout col=lane&15, row=(lane>>4)*4+reg (m89-verified)
  const int rb = (lane >> 4) * 4, cs = lane & 15;
#pragma unroll
  for (int i = 0; i < 4; ++i) {
#pragma unroll
    for (int j = 0; j < 4; ++j) {
#pragma unroll
      for (int r = 0; r < 4; ++r) {
        const int row = m0 + wr * 64 + i * 16 + rb + r;
        const int col = n0 + wc * 64 + j * 16 + cs;
        float v = acc[i][j][r];
        if constexpr (EPI == 0) {
          const int seg = n0 >> 10;
          bf16_t* Cb = (bf16_t*)C + (size_t)seg * 8192 * 1024;
          const float scl = (seg == 0) ? 0.03125f : 1.0f;
          v = (v + bias[col]) * scl;
          Cb[(size_t)row * 1024 + (col & 1023)] = (bf16_t)v;
        } else if constexpr (EPI == 1) {
          ((float*)C)[(size_t)bz * sC + (size_t)row * ldc + col] = v;
        } else {
          ((_Float16*)C)[(size_t)bz * sC + (size_t)row * ldc + col] =
              (_Float16)v;
        }
      }
    }
  }
}

// ---------------------------------------------------------------------------
// row softmax: S fp16 [8192 rows][2048] -> P bf16
// ---------------------------------------------------------------------------
__global__ __launch_bounds__(256) void softmax_k(
    const _Float16* __restrict__ S, bf16_t* __restrict__ P) {
  const long row = blockIdx.x;
  const _Float16* s = S + row * 2048;
  const int tid = threadIdx.x;
  const int wave = tid >> 6, lane = tid & 63;

  float v[8];
  {
    f16x8 hv = *reinterpret_cast<const f16x8*>(s + tid * 8);
#pragma unroll
    for (int k = 0; k < 8; ++k) v[k] = (float)hv[k];
  }
  float m = v[0];
#pragma unroll
  for (int k = 1; k < 8; ++k) m = fmaxf(m, v[k]);
#pragma unroll
  for (int off = 32; off; off >>= 1) m = fmaxf(m, __shfl_xor(m, off));

  __shared__ float red[8];
  if (lane == 0) red[wave] = m;
  __syncthreads();
  m = fmaxf(fmaxf(red[0], red[1]), fmaxf(red[2], red[3]));

  float e[8], sum = 0.f;
#pragma unroll
  for (int k = 0; k < 8; ++k) { e[k] = __expf(v[k] - m); sum += e[k]; }
#pragma unroll
  for (int off = 32; off; off >>= 1) sum += __shfl_xor(sum, off);
  if (lane == 0) red[4 + wave] = sum;
  __syncthreads();
  sum = red[4] + red[5] + red[6] + red[7];
  const float inv = 1.0f / sum;

  bf16x8 o;
#pragma unroll
  for (int k = 0; k < 8; ++k) o[k] = (bf16_t)(e[k] * inv);
  *reinterpret_cast<bf16x8*>(P + row * 2048 + tid * 8) = o;
}

// ---------------------------------------------------------------------------
// launch
// ---------------------------------------------------------------------------
extern "C" void kernel_launch(void* const* d_in, const int* in_sizes, int n_in,
                              void* d_out, int out_size, void* d_ws,
                              size_t ws_size, hipStream_t stream) {
  const float* x = (const float*)d_in[0];  // [4,2048,1024]
  const float* W = (const float*)d_in[1];  // [1024,3072]
  const float* b = (const float*)d_in[2];  // [3072]
  float* out = (float*)d_out;              // [4,2048,1024] fp32

  char* w = (char*)d_ws;
  bf16_t* xb = (bf16_t*)w;    w += (size_t)8192 * 1024 * 2;
  bf16_t* Wt = (bf16_t*)w;    w += (size_t)3072 * 1024 * 2;
  bf16_t* QKV = (bf16_t*)w;   w += (size_t)3 * 8192 * 1024 * 2;
  bf16_t* Vt = (bf16_t*)w;    w += (size_t)4 * 1024 * 2048 * 2;
  _Float16* S = (_Float16*)w; w += (size_t)4 * 2048 * 2048 * 2;
  bf16_t* P = (bf16_t*)w;     w += (size_t)4 * 2048 * 2048 * 2;

  bf16_t* Q = QKV;
  bf16_t* Kd = QKV + (size_t)8192 * 1024;
  bf16_t* V = QKV + (size_t)2 * 8192 * 1024;

  cast_f32_bf16<<<8192, 256, 0, stream>>>(x, xb, (long)8192 * 1024);
  transpose_W<<<dim3(48, 16), 256, 0, stream>>>(W, Wt);

  // Q|K|V dense = x @ W + b (Q scaled 1/32). grid 24x64 = 1536 blocks
  gemm128<0, 32><<<dim3(24, 64, 1), 256, 0, stream>>>(
      xb, Wt, QKV, b, 1024, 1024, 1024, 0, 0, 0);

  transpose_V<<<dim3(16, 32, 4), 256, 0, stream>>>(V, Vt);

  // S = Qs @ K^T, fp16 out. grid 16x16x4 = 1024 blocks
  gemm128<2, 32><<<dim3(16, 16, 4), 256, 0, stream>>>(
      Q, Kd, S, nullptr, 1024, 1024, 2048,
      (long)2048 * 1024, (long)2048 * 1024, (long)2048 * 2048);

  softmax_k<<<8192, 256, 0, stream>>>(S, P);

  // out = P @ Vt^T, fp32 out. grid 8x16x4 = 512 blocks
  gemm128<1, 64><<<dim3(8, 16, 4), 256, 0, stream>>>(
      P, Vt, out, nullptr, 2048, 2048, 1024,
      (long)2048 * 2048, (long)1024 * 2048, (long)2048 * 1024);
}

// Round 8
// 174.926 us; speedup vs baseline: 1.0806x; 1.0427x over previous
//
#include <hip/hip_runtime.h>
#include <hip/hip_bf16.h>
#include <cstdint>
#include <cstddef>

typedef __bf16 bf16_t;
typedef __bf16 bf16x8 __attribute__((ext_vector_type(8)));
typedef __bf16 bf16x4 __attribute__((ext_vector_type(4)));
typedef float f32x4 __attribute__((ext_vector_type(4)));
typedef _Float16 f16x8 __attribute__((ext_vector_type(8)));

#define DEVINL __device__ __forceinline__

DEVINL void gload_lds16(const bf16_t* g, bf16_t* l) {
  __builtin_amdgcn_global_load_lds(
      (__attribute__((address_space(1))) void*)(g),
      (__attribute__((address_space(3))) void*)(l), 16, 0, 0);
}

// ---------------------------------------------------------------------------
// cast fp32 -> bf16
// ---------------------------------------------------------------------------
__global__ __launch_bounds__(256) void cast_f32_bf16(
    const float* __restrict__ in, bf16_t* __restrict__ out, long n) {
  long i = ((long)blockIdx.x * 256 + threadIdx.x) * 4;
  if (i + 3 < n) {
    float4 v = *reinterpret_cast<const float4*>(in + i);
    bf16x4 o = { (bf16_t)v.x, (bf16_t)v.y, (bf16_t)v.z, (bf16_t)v.w };
    *reinterpret_cast<bf16x4*>(out + i) = o;
  }
}

// ---------------------------------------------------------------------------
// W [1024][3072] fp32 -> Wt [3072][1024] bf16
// ---------------------------------------------------------------------------
__global__ __launch_bounds__(256) void transpose_W(
    const float* __restrict__ W, bf16_t* __restrict__ Wt) {
  __shared__ bf16_t tile[64][66];
  const int c0 = blockIdx.x * 64, r0 = blockIdx.y * 64;
  const int tc = threadIdx.x & 63, tr = threadIdx.x >> 6;
#pragma unroll
  for (int k = 0; k < 16; ++k) {
    int rl = k * 4 + tr;
    tile[rl][tc] = (bf16_t)W[(size_t)(r0 + rl) * 3072 + c0 + tc];
  }
  __syncthreads();
#pragma unroll
  for (int k = 0; k < 16; ++k) {
    int cl = k * 4 + tr;
    Wt[(size_t)(c0 + cl) * 1024 + r0 + tc] = tile[tc][cl];
  }
}

// ---------------------------------------------------------------------------
// dense V [8192][1024] -> Vt [b][h][n] bf16
// ---------------------------------------------------------------------------
__global__ __launch_bounds__(256) void transpose_V(
    const bf16_t* __restrict__ V, bf16_t* __restrict__ Vt) {
  __shared__ bf16_t tile[64][66];
  const int b = blockIdx.z;
  const int h0 = blockIdx.x * 64, n0 = blockIdx.y * 64;
  const int tc = threadIdx.x & 63, tr = threadIdx.x >> 6;
#pragma unroll
  for (int k = 0; k < 16; ++k) {
    int nl = k * 4 + tr;
    tile[nl][tc] = V[((size_t)b * 2048 + n0 + nl) * 1024 + h0 + tc];
  }
  __syncthreads();
#pragma unroll
  for (int k = 0; k < 16; ++k) {
    int hl = k * 4 + tr;
    Vt[((size_t)b * 1024 + h0 + hl) * 2048 + n0 + tc] = tile[tc][hl];
  }
}

// ---------------------------------------------------------------------------
// gemm128: C[M][N] = A[M][K] @ B[N][K]^T. 128x128 tile, 4 waves (2x2),
// BK=32 phases, 3 LDS slots (48 KB -> 3 blocks/CU co-resident).
// R8: hierarchical rasterization — XCD-contiguous chunks ordered in bands
// of GM=8 M-rows, column-major within band (i fastest) -> per-XCD in-flight
// window shares 1 B-panel x 8 A-panels (~5 MB vs 8+ MB scattered) ->
// majority-L2-hit staging (targets measured 144 MB vs 22 MB ideal FETCH).
// EPI 0: bf16 dense Q|K|V segs (seg=n0>>10, Q scaled 1/32, +bias)
// EPI 1: fp32 out.   EPI 2: fp16 out.
// ---------------------------------------------------------------------------
template <int EPI, int NQ>
__global__ __launch_bounds__(256, 2) void gemm128(
    const bf16_t* __restrict__ A, const bf16_t* __restrict__ B,
    void* __restrict__ C, const float* __restrict__ bias,
    int lda, int ldb, int ldc, long sA, long sB, long sC) {
  __shared__ bf16_t lds[3][256 * 32];  // slot: A 128x32 | B 128x32

  // XCD chunk + L2 band rasterization (all grids: nwg%8==0, gy%GM==0,
  // chunk%band==0 — verified for the three launch shapes)
  constexpr int GM = 8;
  const int gx = gridDim.x, gy = gridDim.y;
  const int nwg = gx * gy * gridDim.z;
  const int flat = blockIdx.x + gx * (blockIdx.y + gy * blockIdx.z);
  const int v = (flat & 7) * (nwg >> 3) + (flat >> 3);
  const int slice = gx * gy;
  const int bz = v / slice;
  const int rr = v % slice;
  const int BS = GM * gx;
  const int band = rr / BS, tt = rr % BS;
  const int bx = tt / GM;
  const int by = band * GM + (tt % GM);

  const int m0 = by * 128, n0 = bx * 128;
  A += (size_t)bz * sA;
  B += (size_t)bz * sB;

  const int tid = threadIdx.x;
  const int w = tid >> 6, lane = tid & 63;
  const int wr = w >> 1, wc = w & 1;

  // staging source: row = lane>>2, k-chunk = (lane&3)^((lane>>3)&3)  (T2)
  const int srow = lane >> 2;
  const int schunk = ((lane & 3) ^ ((lane >> 3) & 3)) * 8;
  const bf16_t* gA = A + (size_t)(m0 + w * 32 + srow) * lda + schunk;
  const bf16_t* gB = B + (size_t)(n0 + w * 32 + srow) * ldb + schunk;

  const int rsel = lane & 15, kg = lane >> 4;
  const int kswz = (kg ^ ((rsel >> 1) & 3)) * 8;  // T2 read-side XOR
  f32x4 acc[4][4] = {};

#define SA(S, q)                                                              \
  {                                                                           \
    const bf16_t* g = gA + (size_t)(q) * 32;                                  \
    bf16_t* l = &lds[S][(w * 32) * 32];                                       \
    gload_lds16(g, l);                                                        \
    gload_lds16(g + (size_t)16 * lda, l + 16 * 32);                           \
  }
#define SB(S, q)                                                              \
  {                                                                           \
    const bf16_t* g = gB + (size_t)(q) * 32;                                  \
    bf16_t* l = &lds[S][128 * 32 + (w * 32) * 32];                            \
    gload_lds16(g, l);                                                        \
    gload_lds16(g + (size_t)16 * ldb, l + 16 * 32);                           \
  }
#define VMW(N) asm volatile("s_waitcnt vmcnt(%0)" ::"n"(N) : "memory")
#define LKW asm volatile("s_waitcnt lgkmcnt(0)" ::: "memory")
#define BAR __builtin_amdgcn_s_barrier()

  // prologue: stage slots 0,1; complete slot 0
  SA(0, 0); SB(0, 0);
  SA(1, 1); SB(1, 1);
  VMW(4);
  BAR;

#pragma unroll
  for (int q = 0; q < NQ; ++q) {
    const int s = q % 3;
    bf16x8 af[4], bfr[4];
#pragma unroll
    for (int j = 0; j < 4; ++j)
      bfr[j] = *reinterpret_cast<const bf16x8*>(
          &lds[s][128 * 32 + (wc * 64 + j * 16 + rsel) * 32 + kswz]);
#pragma unroll
    for (int i = 0; i < 4; ++i)
      af[i] = *reinterpret_cast<const bf16x8*>(
          &lds[s][(wr * 64 + i * 16 + rsel) * 32 + kswz]);
    if (q + 2 < NQ) {
      const int s2 = (q + 2) % 3;
      SA(s2, q + 2);
      SB(s2, q + 2);
    }
    __builtin_amdgcn_s_setprio(1);
#pragma unroll
    for (int i = 0; i < 4; ++i)
#pragma unroll
      for (int j = 0; j < 4; ++j)
        acc[i][j] = __builtin_amdgcn_mfma_f32_16x16x32_bf16(
            af[i], bfr[j], acc[i][j], 0, 0, 0);
    __builtin_amdgcn_s_setprio(0);
    if (q + 1 < NQ) {
      LKW;  // reads of slot s drained before BAR (WAR vs next-phase stage)
      if (q + 2 < NQ) VMW(4); else VMW(0);
      BAR;
    }
  }
#undef SA
#undef SB
#undef VMW
#undef LKW
#undef BAR

  // epilogue: C/D layout col=lane&15, row=(lane>>4)*4+reg (m89-verified)
  const int rb = (lane >> 4) * 4, cs = lane & 15;
#pragma unroll
  for (int i = 0; i < 4; ++i) {
#pragma unroll
    for (int j = 0; j < 4; ++j) {
#pragma unroll
      for (int r = 0; r < 4; ++r) {
        const int row = m0 + wr * 64 + i * 16 + rb + r;
        const int col = n0 + wc * 64 + j * 16 + cs;
        float v2 = acc[i][j][r];
        if constexpr (EPI == 0) {
          const int seg = n0 >> 10;
          bf16_t* Cb = (bf16_t*)C + (size_t)seg * 8192 * 1024;
          const float scl = (seg == 0) ? 0.03125f : 1.0f;
          v2 = (v2 + bias[col]) * scl;
          Cb[(size_t)row * 1024 + (col & 1023)] = (bf16_t)v2;
        } else if constexpr (EPI == 1) {
          ((float*)C)[(size_t)bz * sC + (size_t)row * ldc + col] = v2;
        } else {
          ((_Float16*)C)[(size_t)bz * sC + (size_t)row * ldc + col] =
              (_Float16)v2;
        }
      }
    }
  }
}

// ---------------------------------------------------------------------------
// row softmax: S fp16 [8192 rows][2048] -> P bf16
// ---------------------------------------------------------------------------
__global__ __launch_bounds__(256) void softmax_k(
    const _Float16* __restrict__ S, bf16_t* __restrict__ P) {
  const long row = blockIdx.x;
  const _Float16* s = S + row * 2048;
  const int tid = threadIdx.x;
  const int wave = tid >> 6, lane = tid & 63;

  float v[8];
  {
    f16x8 hv = *reinterpret_cast<const f16x8*>(s + tid * 8);
#pragma unroll
    for (int k = 0; k < 8; ++k) v[k] = (float)hv[k];
  }
  float m = v[0];
#pragma unroll
  for (int k = 1; k < 8; ++k) m = fmaxf(m, v[k]);
#pragma unroll
  for (int off = 32; off; off >>= 1) m = fmaxf(m, __shfl_xor(m, off));

  __shared__ float red[8];
  if (lane == 0) red[wave] = m;
  __syncthreads();
  m = fmaxf(fmaxf(red[0], red[1]), fmaxf(red[2], red[3]));

  float e[8], sum = 0.f;
#pragma unroll
  for (int k = 0; k < 8; ++k) { e[k] = __expf(v[k] - m); sum += e[k]; }
#pragma unroll
  for (int off = 32; off; off >>= 1) sum += __shfl_xor(sum, off);
  if (lane == 0) red[4 + wave] = sum;
  __syncthreads();
  sum = red[4] + red[5] + red[6] + red[7];
  const float inv = 1.0f / sum;

  bf16x8 o;
#pragma unroll
  for (int k = 0; k < 8; ++k) o[k] = (bf16_t)(e[k] * inv);
  *reinterpret_cast<bf16x8*>(P + row * 2048 + tid * 8) = o;
}

// ---------------------------------------------------------------------------
// launch
// ---------------------------------------------------------------------------
extern "C" void kernel_launch(void* const* d_in, const int* in_sizes, int n_in,
                              void* d_out, int out_size, void* d_ws,
                              size_t ws_size, hipStream_t stream) {
  const float* x = (const float*)d_in[0];  // [4,2048,1024]
  const float* W = (const float*)d_in[1];  // [1024,3072]
  const float* b = (const float*)d_in[2];  // [3072]
  float* out = (float*)d_out;              // [4,2048,1024] fp32

  char* w = (char*)d_ws;
  bf16_t* xb = (bf16_t*)w;    w += (size_t)8192 * 1024 * 2;
  bf16_t* Wt = (bf16_t*)w;    w += (size_t)3072 * 1024 * 2;
  bf16_t* QKV = (bf16_t*)w;   w += (size_t)3 * 8192 * 1024 * 2;
  bf16_t* Vt = (bf16_t*)w;    w += (size_t)4 * 1024 * 2048 * 2;
  _Float16* S = (_Float16*)w; w += (size_t)4 * 2048 * 2048 * 2;
  bf16_t* P = (bf16_t*)w;     w += (size_t)4 * 2048 * 2048 * 2;

  bf16_t* Q = QKV;
  bf16_t* Kd = QKV + (size_t)8192 * 1024;
  bf16_t* V = QKV + (size_t)2 * 8192 * 1024;

  cast_f32_bf16<<<8192, 256, 0, stream>>>(x, xb, (long)8192 * 1024);
  transpose_W<<<dim3(48, 16), 256, 0, stream>>>(W, Wt);

  // Q|K|V dense = x @ W + b (Q scaled 1/32). grid 24x64 = 1536 blocks
  gemm128<0, 32><<<dim3(24, 64, 1), 256, 0, stream>>>(
      xb, Wt, QKV, b, 1024, 1024, 1024, 0, 0, 0);

  transpose_V<<<dim3(16, 32, 4), 256, 0, stream>>>(V, Vt);

  // S = Qs @ K^T, fp16 out. grid 16x16x4 = 1024 blocks
  gemm128<2, 32><<<dim3(16, 16, 4), 256, 0, stream>>>(
      Q, Kd, S, nullptr, 1024, 1024, 2048,
      (long)2048 * 1024, (long)2048 * 1024, (long)2048 * 2048);

  softmax_k<<<8192, 256, 0, stream>>>(S, P);

  // out = P @ Vt^T, fp32 out. grid 8x16x4 = 512 blocks
  gemm128<1, 64><<<dim3(8, 16, 4), 256, 0, stream>>>(
      P, Vt, out, nullptr, 2048, 2048, 1024,
      (long)2048 * 2048, (long)1024 * 2048, (long)2048 * 1024);
}